// Round 7
// baseline (675.749 us; speedup 1.0000x reference)
//
#include <hip/hip_runtime.h>
#include <hip/hip_bf16.h>

#define B_ 64
#define L_ 512
#define H_ 1024
#define EPS_ 1e-13f

typedef unsigned short u16;
typedef __attribute__((ext_vector_type(8))) short s16x8;
typedef __attribute__((ext_vector_type(4))) float f32x4;

__device__ __forceinline__ u16 f2bf(float f) {
  __hip_bfloat16 h = __float2bfloat16(f);
  union { __hip_bfloat16 h; u16 u; } c; c.h = h; return c.u;
}

#define GLOAD(gp, lp)                                                              \
  __builtin_amdgcn_global_load_lds((const __attribute__((address_space(1))) unsigned*)(gp), \
                                   (__attribute__((address_space(3))) unsigned*)(void*)(lp), 16, 0, 0)

// ---- Single fused kernel: softmax (phase 1, own panel -> ws, L2-hot) +
//      deep-pipelined MFMA GEMM with transpose-folded B staging (phase 2).
// 512 blocks x 512 threads. LDS: A ring 3x16KB @0, B ring 2x16KB @49152 = 80KB.
__global__ __launch_bounds__(512, 4) void fused(const float* __restrict__ att,
                                                const float* __restrict__ mask,
                                                const float* __restrict__ X,
                                                u16* __restrict__ Wm,
                                                float* __restrict__ out) {
  const int NT = 16;  // K=512 / BK=32
  // bijective XCD swizzle (grid 512): one batch's 8 tiles co-resident on one XCD
  const int swz = (blockIdx.x & 7) * 64 + (blockIdx.x >> 3);
  const int b  = swz >> 3;
  const int mt = (swz >> 2) & 1;  // M=512 -> 2 tiles of 256
  const int nt = swz & 3;         // N=1024 -> 4 tiles of 256

  __shared__ __align__(16) char lds[81920];

  const int t = threadIdx.x;
  const int lane = t & 63;
  const int w = t >> 6;               // 8 waves
  const int wm = w >> 2, wn = w & 3;  // 2x4 wave grid, 128x64 out each

  u16* gW = Wm + ((size_t)b * L_ + mt * 256) * L_;  // panel: this block writes AND reads it

  // ================= phase 1: softmax of own 256-row panel =================
  {
    const float* gAtt = att + ((size_t)b * L_ + mt * 256) * L_;
    const float* gMask = mask + b * L_ + mt * 256;
#pragma unroll
    for (int rr = 0; rr < 32; rr += 4) {
      const int rbase = w * 32 + rr;
      float a[4][8];
#pragma unroll
      for (int r = 0; r < 4; ++r) {
        const float* p = gAtt + (size_t)(rbase + r) * L_ + lane * 8;
        float4 v0 = *(const float4*)p;
        float4 v1 = *(const float4*)(p + 4);
        a[r][0] = v0.x; a[r][1] = v0.y; a[r][2] = v0.z; a[r][3] = v0.w;
        a[r][4] = v1.x; a[r][5] = v1.y; a[r][6] = v1.z; a[r][7] = v1.w;
      }
      float m[4];
#pragma unroll
      for (int r = 0; r < 4; ++r) {
        m[r] = a[r][0];
#pragma unroll
        for (int j = 1; j < 8; ++j) m[r] = fmaxf(m[r], a[r][j]);
      }
#pragma unroll
      for (int off = 32; off > 0; off >>= 1)
#pragma unroll
        for (int r = 0; r < 4; ++r) m[r] = fmaxf(m[r], __shfl_xor(m[r], off));
      float z[4] = {0.f, 0.f, 0.f, 0.f};
#pragma unroll
      for (int r = 0; r < 4; ++r)
#pragma unroll
        for (int j = 0; j < 8; ++j) { a[r][j] = __expf(a[r][j] - m[r]); z[r] += a[r][j]; }
#pragma unroll
      for (int off = 32; off > 0; off >>= 1)
#pragma unroll
        for (int r = 0; r < 4; ++r) z[r] += __shfl_xor(z[r], off);
#pragma unroll
      for (int r = 0; r < 4; ++r) {
        const float mk = gMask[rbase + r];
        const float c = (1.0f / z[r]) * (mk / (mk + EPS_));  // softmax row-sum == 1
        union { u16 u[8]; uint4 v; } wv;
#pragma unroll
        for (int j = 0; j < 8; ++j) wv.u[j] = f2bf(a[r][j] * c);
        *(uint4*)(gW + (size_t)(rbase + r) * L_ + lane * 8) = wv.v;
      }
    }
  }
  __threadfence_block();
  __syncthreads();  // gW visible to own block's global_load_lds

  // ================= phase 2: deep-pipelined GEMM =================
  const float* gX = X + (size_t)b * L_ * H_ + nt * 256;  // [k][n'] with n' = col offset

  // A staging via global_load_lds (r5-proven): rows r0 / r0+128, 16B slot t&3
  const int r0 = t >> 2;
  const int xsw = (r0 & 3) ^ ((r0 >> 2) & 3);
  const int scol = ((t & 3) ^ xsw) * 8;
  const u16* pA0 = gW + (size_t)r0 * L_ + scol;
  char* dA = lds + w * 1024;  // + region*16384 (+8192 for rows 128..255)

  // B staging (reg-staged X f32 -> bf16, transposed [n][k] LDS layout)
  const int bn = t & 255;           // n within tile
  const int kg0 = (t >> 8) * 2;     // k-group base (each thread: kg0, kg0+1)
  const float* pX0 = gX + bn;

  // frag byte offsets
  int offA[8], offB[4];
#pragma unroll
  for (int mf = 0; mf < 8; ++mf) {
    int r = wm * 128 + mf * 16 + (lane & 15);
    offA[mf] = r * 64 + ((((lane >> 4) ^ (r & 3) ^ ((r >> 2) & 3))) << 4);
  }
#pragma unroll
  for (int nf = 0; nf < 4; ++nf) {
    int r = wn * 64 + nf * 16 + (lane & 15);
    offB[nf] = 49152 + r * 64 + ((((lane >> 4) ^ ((r >> 2) & 3))) << 4);
  }

  f32x4 acc[8][4] = {};
  float bx[2][2][8];  // [tile parity][kg sub][j] — all compile-time indices

#define A_ISSUE(tt)                                                       \
  do {                                                                    \
    GLOAD(pA0 + (tt) * 32, dA + ((tt) % 3) * 16384);                      \
    GLOAD(pA0 + (tt) * 32 + 128 * (size_t)L_, dA + ((tt) % 3) * 16384 + 8192); \
  } while (0)

#define B_ISSUE(tt)                                                       \
  do {                                                                    \
    _Pragma("unroll")                                                     \
    for (int g = 0; g < 2; ++g)                                           \
      _Pragma("unroll")                                                   \
      for (int j = 0; j < 8; ++j)                                         \
        bx[(tt) & 1][g][j] = pX0[(size_t)((tt) * 32 + (kg0 + g) * 8 + j) * H_]; \
  } while (0)

#define B_CVT_WRITE(tt)                                                   \
  do {                                                                    \
    _Pragma("unroll")                                                     \
    for (int g = 0; g < 2; ++g) {                                         \
      union { u16 u[8]; uint4 v; } pk;                                    \
      _Pragma("unroll")                                                   \
      for (int j = 0; j < 8; ++j) pk.u[j] = f2bf(bx[(tt) & 1][g][j]);     \
      int kg = kg0 + g;                                                   \
      *(uint4*)(lds + 49152 + ((tt) & 1) * 16384 + bn * 64 +              \
                ((kg ^ ((bn >> 2) & 3)) << 4)) = pk.v;                    \
    }                                                                     \
  } while (0)

  // prologue: tiles 0,1 in flight
  A_ISSUE(0); B_ISSUE(0); A_ISSUE(1); B_ISSUE(1);
  asm volatile("s_waitcnt vmcnt(18)" ::: "memory");  // tile 0 (A 2 + B 16) done
  B_CVT_WRITE(0);
  asm volatile("s_waitcnt lgkmcnt(0)" ::: "memory");
  __builtin_amdgcn_s_barrier();

#pragma unroll
  for (int k = 0; k < NT; ++k) {
    if (k + 2 < NT) { A_ISSUE(k + 2); B_ISSUE(k + 2); }

    const char* baseA = lds + (k % 3) * 16384;
    const char* baseB = lds + (k & 1) * 16384;  // offB carries +49152
    s16x8 af[8], bf4[4];
#pragma unroll
    for (int mf = 0; mf < 8; ++mf) af[mf] = *(const s16x8*)(baseA + offA[mf]);
#pragma unroll
    for (int nf = 0; nf < 4; ++nf) bf4[nf] = *(const s16x8*)(baseB + offB[nf]);
    asm volatile("s_waitcnt lgkmcnt(0)" ::: "memory");

    __builtin_amdgcn_s_setprio(1);
#pragma unroll
    for (int mf = 0; mf < 8; ++mf)
#pragma unroll
      for (int nf = 0; nf < 4; ++nf)
        acc[mf][nf] = __builtin_amdgcn_mfma_f32_16x16x32_bf16(af[mf], bf4[nf], acc[mf][nf], 0, 0, 0);
    __builtin_amdgcn_s_setprio(0);

    if (k + 1 < NT) {
      // publish tile k+1: its A gload (and B regloads) must be complete in every
      // wave BEFORE the barrier below.
      if (k + 2 < NT) asm volatile("s_waitcnt vmcnt(18)" ::: "memory");
      else            asm volatile("s_waitcnt vmcnt(0)" ::: "memory");
      B_CVT_WRITE(k + 1);
      asm volatile("s_waitcnt lgkmcnt(0)" ::: "memory");
      __builtin_amdgcn_s_barrier();
    }
  }
#undef A_ISSUE
#undef B_ISSUE
#undef B_CVT_WRITE

  // epilogue: C/D layout col=lane&15, row=(lane>>4)*4+reg  [verified m89/m91]
  const int orow0 = mt * 256 + wm * 128 + ((lane >> 4) << 2);
  const int ocol0 = nt * 256 + wn * 64 + (lane & 15);
#pragma unroll
  for (int mf = 0; mf < 8; ++mf)
#pragma unroll
    for (int nf = 0; nf < 4; ++nf)
#pragma unroll
      for (int j = 0; j < 4; ++j) {
        int row = orow0 + mf * 16 + j;
        int col = ocol0 + nf * 16;
        out[((size_t)b * L_ + row) * H_ + col] = acc[mf][nf][j];
      }
}

extern "C" void kernel_launch(void* const* d_in, const int* in_sizes, int n_in,
                              void* d_out, int out_size, void* d_ws, size_t ws_size,
                              hipStream_t stream) {
  (void)in_sizes; (void)n_in; (void)out_size; (void)ws_size;
  const float* sent = (const float*)d_in[0];  // [B, L, H] f32
  const float* mask = (const float*)d_in[1];  // [B, L]    f32
  const float* att  = (const float*)d_in[2];  // [B, L, L] f32
  u16* Wm = (u16*)d_ws;                       // [B, L, L] bf16 (32 MiB) — W panels
  float* outp = (float*)d_out;                // [B, L, H] f32

  fused<<<B_ * 2 * 4, 512, 0, stream>>>(att, mask, sent, Wm, outp);
}

// Round 8
// 116.253 us; speedup vs baseline: 5.8127x; 5.8127x over previous
//
#include <hip/hip_runtime.h>
#include <hip/hip_bf16.h>

#define B_ 64
#define L_ 512
#define H_ 1024
#define EPS_ 1e-13f

typedef unsigned short u16;
typedef __attribute__((ext_vector_type(8))) short s16x8;
typedef __attribute__((ext_vector_type(4))) float f32x4;

__device__ __forceinline__ u16 f2bf(float f) {
  __hip_bfloat16 h = __float2bfloat16(f);
  union { __hip_bfloat16 h; u16 u; } c; c.h = h; return c.u;
}

#define GLOAD(gp, lp)                                                              \
  __builtin_amdgcn_global_load_lds((const __attribute__((address_space(1))) unsigned*)(gp), \
                                   (__attribute__((address_space(3))) unsigned*)(void*)(lp), 16, 0, 0)

// ---- Single fused kernel: softmax (phase 1, own panel -> ws, L2-hot) +
//      deep-pipelined MFMA GEMM with transpose-folded B staging (phase 2).
// 512 blocks x 512 threads. LDS: A ring 3x16KB @0, B ring 2x16KB @49152 = 80KB.
// __launch_bounds__(512,2): 2 waves/EU min -> 256-reg budget. (512,4) in r7
// capped regs at 128 total (VGPR 64 + AGPR) and spilled 1.35 GB to scratch.
__global__ __launch_bounds__(512, 2) void fused(const float* __restrict__ att,
                                                const float* __restrict__ mask,
                                                const float* __restrict__ X,
                                                u16* __restrict__ Wm,
                                                float* __restrict__ out) {
  const int NT = 16;  // K=512 / BK=32
  // bijective XCD swizzle (grid 512): one batch's 8 tiles co-resident on one XCD
  const int swz = (blockIdx.x & 7) * 64 + (blockIdx.x >> 3);
  const int b  = swz >> 3;
  const int mt = (swz >> 2) & 1;  // M=512 -> 2 tiles of 256
  const int nt = swz & 3;         // N=1024 -> 4 tiles of 256

  __shared__ __align__(16) char lds[81920];

  const int t = threadIdx.x;
  const int lane = t & 63;
  const int w = t >> 6;               // 8 waves
  const int wm = w >> 2, wn = w & 3;  // 2x4 wave grid, 128x64 out each

  u16* gW = Wm + ((size_t)b * L_ + mt * 256) * L_;  // panel: this block writes AND reads it

  // ================= phase 1: softmax of own 256-row panel =================
  {
    const float* gAtt = att + ((size_t)b * L_ + mt * 256) * L_;
    const float* gMask = mask + b * L_ + mt * 256;
#pragma unroll
    for (int rr = 0; rr < 32; rr += 4) {
      const int rbase = w * 32 + rr;
      float a[4][8];
#pragma unroll
      for (int r = 0; r < 4; ++r) {
        const float* p = gAtt + (size_t)(rbase + r) * L_ + lane * 8;
        float4 v0 = *(const float4*)p;
        float4 v1 = *(const float4*)(p + 4);
        a[r][0] = v0.x; a[r][1] = v0.y; a[r][2] = v0.z; a[r][3] = v0.w;
        a[r][4] = v1.x; a[r][5] = v1.y; a[r][6] = v1.z; a[r][7] = v1.w;
      }
      float m[4];
#pragma unroll
      for (int r = 0; r < 4; ++r) {
        m[r] = a[r][0];
#pragma unroll
        for (int j = 1; j < 8; ++j) m[r] = fmaxf(m[r], a[r][j]);
      }
#pragma unroll
      for (int off = 32; off > 0; off >>= 1)
#pragma unroll
        for (int r = 0; r < 4; ++r) m[r] = fmaxf(m[r], __shfl_xor(m[r], off));
      float z[4] = {0.f, 0.f, 0.f, 0.f};
#pragma unroll
      for (int r = 0; r < 4; ++r)
#pragma unroll
        for (int j = 0; j < 8; ++j) { a[r][j] = __expf(a[r][j] - m[r]); z[r] += a[r][j]; }
#pragma unroll
      for (int off = 32; off > 0; off >>= 1)
#pragma unroll
        for (int r = 0; r < 4; ++r) z[r] += __shfl_xor(z[r], off);
#pragma unroll
      for (int r = 0; r < 4; ++r) {
        const float mk = gMask[rbase + r];
        const float c = (1.0f / z[r]) * (mk / (mk + EPS_));  // softmax row-sum == 1
        union { u16 u[8]; uint4 v; } wv;
#pragma unroll
        for (int j = 0; j < 8; ++j) wv.u[j] = f2bf(a[r][j] * c);
        *(uint4*)(gW + (size_t)(rbase + r) * L_ + lane * 8) = wv.v;
      }
    }
  }
  __threadfence_block();
  __syncthreads();  // gW visible to own block's global_load_lds

  // ================= phase 2: deep-pipelined GEMM =================
  const float* gX = X + (size_t)b * L_ * H_ + nt * 256;  // [k][n'] with n' = col offset

  // A staging via global_load_lds (r5-proven): rows r0 / r0+128, 16B slot t&3
  const int r0 = t >> 2;
  const int xsw = (r0 & 3) ^ ((r0 >> 2) & 3);
  const int scol = ((t & 3) ^ xsw) * 8;
  const u16* pA0 = gW + (size_t)r0 * L_ + scol;
  char* dA = lds + w * 1024;  // + region*16384 (+8192 for rows 128..255)

  // B staging (reg-staged X f32 -> bf16, transposed [n][k] LDS layout)
  const int bn = t & 255;           // n within tile
  const int kg0 = (t >> 8) * 2;     // k-group base (each thread: kg0, kg0+1)
  const float* pX0 = gX + bn;

  // frag byte offsets
  int offA[8], offB[4];
#pragma unroll
  for (int mf = 0; mf < 8; ++mf) {
    int r = wm * 128 + mf * 16 + (lane & 15);
    offA[mf] = r * 64 + ((((lane >> 4) ^ (r & 3) ^ ((r >> 2) & 3))) << 4);
  }
#pragma unroll
  for (int nf = 0; nf < 4; ++nf) {
    int r = wn * 64 + nf * 16 + (lane & 15);
    offB[nf] = 49152 + r * 64 + ((((lane >> 4) ^ ((r >> 2) & 3))) << 4);
  }

  f32x4 acc[8][4] = {};
  float bx[2][2][8];  // [tile parity][kg sub][j] — all compile-time indices

#define A_ISSUE(tt)                                                       \
  do {                                                                    \
    GLOAD(pA0 + (tt) * 32, dA + ((tt) % 3) * 16384);                      \
    GLOAD(pA0 + (tt) * 32 + 128 * (size_t)L_, dA + ((tt) % 3) * 16384 + 8192); \
  } while (0)

#define B_ISSUE(tt)                                                       \
  do {                                                                    \
    _Pragma("unroll")                                                     \
    for (int g = 0; g < 2; ++g)                                           \
      _Pragma("unroll")                                                   \
      for (int j = 0; j < 8; ++j)                                         \
        bx[(tt) & 1][g][j] = pX0[(size_t)((tt) * 32 + (kg0 + g) * 8 + j) * H_]; \
  } while (0)

#define B_CVT_WRITE(tt)                                                   \
  do {                                                                    \
    _Pragma("unroll")                                                     \
    for (int g = 0; g < 2; ++g) {                                         \
      union { u16 u[8]; uint4 v; } pk;                                    \
      _Pragma("unroll")                                                   \
      for (int j = 0; j < 8; ++j) pk.u[j] = f2bf(bx[(tt) & 1][g][j]);     \
      int kg = kg0 + g;                                                   \
      *(uint4*)(lds + 49152 + ((tt) & 1) * 16384 + bn * 64 +              \
                ((kg ^ ((bn >> 2) & 3)) << 4)) = pk.v;                    \
    }                                                                     \
  } while (0)

  // prologue: tiles 0,1 in flight
  A_ISSUE(0); B_ISSUE(0); A_ISSUE(1); B_ISSUE(1);
  asm volatile("s_waitcnt vmcnt(18)" ::: "memory");  // tile 0 (A 2 + B 16) done
  B_CVT_WRITE(0);
  asm volatile("s_waitcnt lgkmcnt(0)" ::: "memory");
  __builtin_amdgcn_s_barrier();

#pragma unroll
  for (int k = 0; k < NT; ++k) {
    if (k + 2 < NT) { A_ISSUE(k + 2); B_ISSUE(k + 2); }

    const char* baseA = lds + (k % 3) * 16384;
    const char* baseB = lds + (k & 1) * 16384;  // offB carries +49152
    s16x8 af[8], bf4[4];
#pragma unroll
    for (int mf = 0; mf < 8; ++mf) af[mf] = *(const s16x8*)(baseA + offA[mf]);
#pragma unroll
    for (int nf = 0; nf < 4; ++nf) bf4[nf] = *(const s16x8*)(baseB + offB[nf]);
    asm volatile("s_waitcnt lgkmcnt(0)" ::: "memory");

    __builtin_amdgcn_s_setprio(1);
#pragma unroll
    for (int mf = 0; mf < 8; ++mf)
#pragma unroll
      for (int nf = 0; nf < 4; ++nf)
        acc[mf][nf] = __builtin_amdgcn_mfma_f32_16x16x32_bf16(af[mf], bf4[nf], acc[mf][nf], 0, 0, 0);
    __builtin_amdgcn_s_setprio(0);

    if (k + 1 < NT) {
      // publish tile k+1: its A gload (and B regloads) must be complete in every
      // wave BEFORE the barrier below.
      if (k + 2 < NT) asm volatile("s_waitcnt vmcnt(18)" ::: "memory");
      else            asm volatile("s_waitcnt vmcnt(0)" ::: "memory");
      B_CVT_WRITE(k + 1);
      asm volatile("s_waitcnt lgkmcnt(0)" ::: "memory");
      __builtin_amdgcn_s_barrier();
    }
  }
#undef A_ISSUE
#undef B_ISSUE
#undef B_CVT_WRITE

  // epilogue: C/D layout col=lane&15, row=(lane>>4)*4+reg  [verified m89/m91]
  const int orow0 = mt * 256 + wm * 128 + ((lane >> 4) << 2);
  const int ocol0 = nt * 256 + wn * 64 + (lane & 15);
#pragma unroll
  for (int mf = 0; mf < 8; ++mf)
#pragma unroll
    for (int nf = 0; nf < 4; ++nf)
#pragma unroll
      for (int j = 0; j < 4; ++j) {
        int row = orow0 + mf * 16 + j;
        int col = ocol0 + nf * 16;
        out[((size_t)b * L_ + row) * H_ + col] = acc[mf][nf][j];
      }
}

extern "C" void kernel_launch(void* const* d_in, const int* in_sizes, int n_in,
                              void* d_out, int out_size, void* d_ws, size_t ws_size,
                              hipStream_t stream) {
  (void)in_sizes; (void)n_in; (void)out_size; (void)ws_size;
  const float* sent = (const float*)d_in[0];  // [B, L, H] f32
  const float* mask = (const float*)d_in[1];  // [B, L]    f32
  const float* att  = (const float*)d_in[2];  // [B, L, L] f32
  u16* Wm = (u16*)d_ws;                       // [B, L, L] bf16 (32 MiB) — W panels
  float* outp = (float*)d_out;                // [B, L, H] f32

  fused<<<B_ * 2 * 4, 512, 0, stream>>>(att, mask, sent, Wm, outp);
}

// Round 9
// 96.134 us; speedup vs baseline: 7.0293x; 1.2093x over previous
//
#include <hip/hip_runtime.h>
#include <hip/hip_bf16.h>

#define B_ 64
#define L_ 512
#define H_ 1024
#define EPS_ 1e-13f

typedef unsigned short u16;
typedef __attribute__((ext_vector_type(8))) short s16x8;
typedef __attribute__((ext_vector_type(4))) float f32x4;

__device__ __forceinline__ u16 f2bf(float f) {
  __hip_bfloat16 h = __float2bfloat16(f);
  union { __hip_bfloat16 h; u16 u; } c; c.h = h; return c.u;
}

// ---- Kernel 1: row softmax + mask renorm -> W bf16 (1x work, BW-bound). ----
__global__ __launch_bounds__(256) void softmax_rows(const float* __restrict__ att,
                                                    const float* __restrict__ mask,
                                                    u16* __restrict__ Wout) {
  const int w = threadIdx.x >> 6, lane = threadIdx.x & 63;
  const int row0 = blockIdx.x * 16 + w * 4;

  float a[4][8];
#pragma unroll
  for (int r = 0; r < 4; ++r) {
    const float* p = att + (size_t)(row0 + r) * L_ + lane * 8;
    float4 v0 = *(const float4*)p;
    float4 v1 = *(const float4*)(p + 4);
    a[r][0] = v0.x; a[r][1] = v0.y; a[r][2] = v0.z; a[r][3] = v0.w;
    a[r][4] = v1.x; a[r][5] = v1.y; a[r][6] = v1.z; a[r][7] = v1.w;
  }

  float m[4];
#pragma unroll
  for (int r = 0; r < 4; ++r) {
    m[r] = a[r][0];
#pragma unroll
    for (int j = 1; j < 8; ++j) m[r] = fmaxf(m[r], a[r][j]);
  }
#pragma unroll
  for (int off = 32; off > 0; off >>= 1)
#pragma unroll
    for (int r = 0; r < 4; ++r) m[r] = fmaxf(m[r], __shfl_xor(m[r], off));

  float z[4] = {0.f, 0.f, 0.f, 0.f};
#pragma unroll
  for (int r = 0; r < 4; ++r)
#pragma unroll
    for (int j = 0; j < 8; ++j) { a[r][j] = __expf(a[r][j] - m[r]); z[r] += a[r][j]; }
#pragma unroll
  for (int off = 32; off > 0; off >>= 1)
#pragma unroll
    for (int r = 0; r < 4; ++r) z[r] += __shfl_xor(z[r], off);

#pragma unroll
  for (int r = 0; r < 4; ++r) {
    const float mk = mask[row0 + r];
    const float c = (1.0f / z[r]) * (mk / (mk + EPS_));  // softmax row-sum == 1
    union { u16 u[8]; uint4 v; } wv;
#pragma unroll
    for (int j = 0; j < 8; ++j) wv.u[j] = f2bf(a[r][j] * c);
    *(uint4*)(Wout + (size_t)(row0 + r) * L_ + lane * 8) = wv.v;
  }
}

#define GLOAD(gp, lp)                                                              \
  __builtin_amdgcn_global_load_lds((const __attribute__((address_space(1))) unsigned*)(gp), \
                                   (__attribute__((address_space(3))) unsigned*)(void*)(lp), 16, 0, 0)

// ---- Kernel 2: GEMM out = W @ X, B staged DIRECTLY from X f32 (transpose
// folded into staging; no XT intermediate). 256x256 tile, 8 waves, deep
// pipeline (A ring 3x16KB via global_load_lds, B ring 2x16KB reg-staged
// f32->bf16 [n][k]), counted vmcnt(18), setprio. Byte-identical to r8 phase 2.
__global__ __launch_bounds__(512, 2) void gemm_xd(const u16* __restrict__ Wm,
                                                  const float* __restrict__ X,
                                                  float* __restrict__ out) {
  const int NT = 16;  // K=512 / BK=32
  const int swz = (blockIdx.x & 7) * 64 + (blockIdx.x >> 3);
  const int b  = swz >> 3;
  const int mt = (swz >> 2) & 1;  // M=512 -> 2 tiles of 256
  const int nt = swz & 3;         // N=1024 -> 4 tiles of 256

  __shared__ __align__(16) char lds[81920];

  const int t = threadIdx.x;
  const int lane = t & 63;
  const int w = t >> 6;               // 8 waves
  const int wm = w >> 2, wn = w & 3;  // 2x4 wave grid, 128x64 out each

  const u16* gW = Wm + ((size_t)b * L_ + mt * 256) * L_;  // L3-hot (33 MB total)
  const float* gX = X + (size_t)b * L_ * H_ + nt * 256;

  // A staging via global_load_lds: rows r0 / r0+128, 16B slot t&3
  const int r0 = t >> 2;
  const int xsw = (r0 & 3) ^ ((r0 >> 2) & 3);
  const int scol = ((t & 3) ^ xsw) * 8;
  const u16* pA0 = gW + (size_t)r0 * L_ + scol;
  char* dA = lds + w * 1024;  // + region*16384 (+8192 for rows 128..255)

  // B staging (reg-staged X f32 -> bf16, transposed [n][k] LDS layout)
  const int bn = t & 255;           // n within tile
  const int kg0 = (t >> 8) * 2;     // k-group base (each thread: kg0, kg0+1)
  const float* pX0 = gX + bn;

  int offA[8], offB[4];
#pragma unroll
  for (int mf = 0; mf < 8; ++mf) {
    int r = wm * 128 + mf * 16 + (lane & 15);
    offA[mf] = r * 64 + ((((lane >> 4) ^ (r & 3) ^ ((r >> 2) & 3))) << 4);
  }
#pragma unroll
  for (int nf = 0; nf < 4; ++nf) {
    int r = wn * 64 + nf * 16 + (lane & 15);
    offB[nf] = 49152 + r * 64 + ((((lane >> 4) ^ ((r >> 2) & 3))) << 4);
  }

  f32x4 acc[8][4] = {};
  float bx[2][2][8];  // [tile parity][kg sub][j] — compile-time indices only

#define A_ISSUE(tt)                                                       \
  do {                                                                    \
    GLOAD(pA0 + (tt) * 32, dA + ((tt) % 3) * 16384);                      \
    GLOAD(pA0 + (tt) * 32 + 128 * (size_t)L_, dA + ((tt) % 3) * 16384 + 8192); \
  } while (0)

#define B_ISSUE(tt)                                                       \
  do {                                                                    \
    _Pragma("unroll")                                                     \
    for (int g = 0; g < 2; ++g)                                           \
      _Pragma("unroll")                                                   \
      for (int j = 0; j < 8; ++j)                                         \
        bx[(tt) & 1][g][j] = pX0[(size_t)((tt) * 32 + (kg0 + g) * 8 + j) * H_]; \
  } while (0)

#define B_CVT_WRITE(tt)                                                   \
  do {                                                                    \
    _Pragma("unroll")                                                     \
    for (int g = 0; g < 2; ++g) {                                         \
      union { u16 u[8]; uint4 v; } pk;                                    \
      _Pragma("unroll")                                                   \
      for (int j = 0; j < 8; ++j) pk.u[j] = f2bf(bx[(tt) & 1][g][j]);     \
      int kg = kg0 + g;                                                   \
      *(uint4*)(lds + 49152 + ((tt) & 1) * 16384 + bn * 64 +              \
                ((kg ^ ((bn >> 2) & 3)) << 4)) = pk.v;                    \
    }                                                                     \
  } while (0)

  // prologue: tiles 0,1 in flight (18 vmem ops each)
  A_ISSUE(0); B_ISSUE(0); A_ISSUE(1); B_ISSUE(1);
  asm volatile("s_waitcnt vmcnt(18)" ::: "memory");  // tile 0 done
  B_CVT_WRITE(0);
  asm volatile("s_waitcnt lgkmcnt(0)" ::: "memory");
  __builtin_amdgcn_s_barrier();

#pragma unroll
  for (int k = 0; k < NT; ++k) {
    if (k + 2 < NT) { A_ISSUE(k + 2); B_ISSUE(k + 2); }

    const char* baseA = lds + (k % 3) * 16384;
    const char* baseB = lds + (k & 1) * 16384;  // offB carries +49152
    s16x8 af[8], bf4[4];
#pragma unroll
    for (int mf = 0; mf < 8; ++mf) af[mf] = *(const s16x8*)(baseA + offA[mf]);
#pragma unroll
    for (int nf = 0; nf < 4; ++nf) bf4[nf] = *(const s16x8*)(baseB + offB[nf]);
    asm volatile("s_waitcnt lgkmcnt(0)" ::: "memory");

    __builtin_amdgcn_s_setprio(1);
#pragma unroll
    for (int mf = 0; mf < 8; ++mf)
#pragma unroll
      for (int nf = 0; nf < 4; ++nf)
        acc[mf][nf] = __builtin_amdgcn_mfma_f32_16x16x32_bf16(af[mf], bf4[nf], acc[mf][nf], 0, 0, 0);
    __builtin_amdgcn_s_setprio(0);

    if (k + 1 < NT) {
      if (k + 2 < NT) asm volatile("s_waitcnt vmcnt(18)" ::: "memory");
      else            asm volatile("s_waitcnt vmcnt(0)" ::: "memory");
      B_CVT_WRITE(k + 1);
      asm volatile("s_waitcnt lgkmcnt(0)" ::: "memory");
      __builtin_amdgcn_s_barrier();
    }
  }
#undef A_ISSUE
#undef B_ISSUE
#undef B_CVT_WRITE

  // epilogue: C/D layout col=lane&15, row=(lane>>4)*4+reg  [verified m89/m91]
  const int orow0 = mt * 256 + wm * 128 + ((lane >> 4) << 2);
  const int ocol0 = nt * 256 + wn * 64 + (lane & 15);
#pragma unroll
  for (int mf = 0; mf < 8; ++mf)
#pragma unroll
    for (int nf = 0; nf < 4; ++nf)
#pragma unroll
      for (int j = 0; j < 4; ++j) {
        int row = orow0 + mf * 16 + j;
        int col = ocol0 + nf * 16;
        out[((size_t)b * L_ + row) * H_ + col] = acc[mf][nf][j];
      }
}

extern "C" void kernel_launch(void* const* d_in, const int* in_sizes, int n_in,
                              void* d_out, int out_size, void* d_ws, size_t ws_size,
                              hipStream_t stream) {
  (void)in_sizes; (void)n_in; (void)out_size; (void)ws_size;
  const float* sent = (const float*)d_in[0];  // [B, L, H] f32
  const float* mask = (const float*)d_in[1];  // [B, L]    f32
  const float* att  = (const float*)d_in[2];  // [B, L, L] f32
  u16* Wm = (u16*)d_ws;                       // [B, L, L] bf16 (32 MiB)
  float* outp = (float*)d_out;                // [B, L, H] f32

  softmax_rows<<<2048, 256, 0, stream>>>(att, mask, Wm);
  gemm_xd<<<B_ * 2 * 4, 512, 0, stream>>>(Wm, sent, outp);
}